// Round 16
// baseline (117.723 us; speedup 1.0000x reference)
//
#include <hip/hip_runtime.h>

#define Wd 640
#define Hd 512
#define NB 32
#define TW 64
#define TH 16
#define RR 4
#define SWP 38                      // LDS row stride in u32 pairs (36 used + 2 pad)
constexpr int TILES_X = Wd / TW;   // 10
constexpr int TILES_Y = Hd / TH;   // 32
constexpr int NBLK = TILES_X * TILES_Y * NB;   // 10240
constexpr size_t HWsz = (size_t)Hd * Wd;

typedef __fp16 h2 __attribute__((ext_vector_type(2)));
union HU { unsigned u; h2 h; };
__device__ __forceinline__ h2 u2h(unsigned u){ HU c; c.u = u; return c.h; }
__device__ __forceinline__ h2 habs2(h2 x){ HU c; c.h = x; c.u &= 0x7fff7fffu; return c.h; }
__device__ __forceinline__ unsigned pack2(float a, float b)
{
    HU c; c.h = __builtin_amdgcn_cvt_pkrtz(a, b); return c.u;
}

// ---------------- Kernel A: disparity warp ----------------
__global__ __launch_bounds__(256)
void warp_kernel(const float* __restrict__ disp, const float* __restrict__ pattern,
                 float* __restrict__ proj)
{
    int gid = blockIdx.x * 256 + threadIdx.x;
    int n = gid * 4;
    float4 d4 = *(const float4*)(disp + n);
    int u = n % Wd;
    int rowbase = ((n / Wd) % Hd) * Wd;
    float dv[4] = {d4.x, d4.y, d4.z, d4.w};
    #pragma unroll
    for (int j = 0; j < 4; ++j) {
        float x = (float)(u + j) - dv[j];
        x = fminf(fmaxf(x, 0.f), (float)(Wd - 1));
        float x0 = floorf(x);
        float w = x - x0;
        int i0 = (int)x0;
        int i1 = min(i0 + 1, Wd - 1);
        float g0 = pattern[rowbase + i0];
        float g1 = pattern[rowbase + i1];
        proj[n + j] = fmaf(w, g1 - g0, g0);
    }
}

// ---------------- packed census primitives (r13/r14-proven) ----------------
#define PKTM(CA,CB, NAu,NBu, MM, N,E) {            \
    h2 _da = u2h(NAu) - CA;                        \
    h2 _db = u2h(NBu) - CB;                        \
    h2 _d1 = h05 + habs2(_da);                     \
    h2 _d2 = h05 + habs2(_db);                     \
    N = _da * _d2 - _db * _d1;                     \
    if constexpr (EC) N = N * u2h(MM);             \
    E = _d1 * _d2; }

#define L1C(N1,E1,N2,E2, SP,EP) {                  \
    SP = habs2(N1) * E2 + habs2(N2) * E1;          \
    EP = E1 * E2; }

#define UNP(S,E, MV, P0,P1) {                      \
    float _sl = (float)S[0], _sh = (float)S[1];    \
    float _el = (float)E[0], _eh = (float)E[1];    \
    if constexpr (ER) { _sl *= MV; _sh *= MV; }    \
    P0 = fmaf(_sl, __builtin_amdgcn_rcpf(_el), P0);\
    P1 = fmaf(_sh, __builtin_amdgcn_rcpf(_eh), P1); }

#define ROWJOB(CA,CB, A0,A1,A2,A3,A4,A5,A6,A7,A8,  \
                      B0,B1,B2,B3,B4,B5,B6,B7,B8,  \
                      M0,M1,M2,M3,M4,M5,M6,M7,M8, MV, P0,P1) { \
    h2 n0,e0,n1,e1,n2,e2,n3,e3,n4,e4,n5,e5,n6,e6,n7,e7,n8,e8; \
    PKTM(CA,CB, A0,B0, M0, n0,e0)                  \
    PKTM(CA,CB, A1,B1, M1, n1,e1)                  \
    PKTM(CA,CB, A2,B2, M2, n2,e2)                  \
    PKTM(CA,CB, A3,B3, M3, n3,e3)                  \
    PKTM(CA,CB, A4,B4, M4, n4,e4)                  \
    PKTM(CA,CB, A5,B5, M5, n5,e5)                  \
    PKTM(CA,CB, A6,B6, M6, n6,e6)                  \
    PKTM(CA,CB, A7,B7, M7, n7,e7)                  \
    PKTM(CA,CB, A8,B8, M8, n8,e8)                  \
    h2 s01,e01,s23,e23,s45,e45,s67,e67;            \
    L1C(n0,e0,n1,e1, s01,e01)                      \
    L1C(n2,e2,n3,e3, s23,e23)                      \
    L1C(n4,e4,n5,e5, s45,e45)                      \
    L1C(n6,e6,n7,e7, s67,e67)                      \
    h2 sL = s01*e23 + s23*e01;  h2 eL = e01*e23;   \
    h2 sR = s45*e67 + s67*e45;  h2 eR = e45*e67;   \
    sR = sR*e8 + habs2(n8)*eR;  eR = eR*e8;        \
    h2 S = sL*eR + sR*eL;       h2 E = eL*eR;      \
    UNP(S,E, MV, P0,P1) }

#define CTR4(CA,CB, A1,A2,A3,A4, B1,B2,B3,B4, M1,M2,M3,M4, P0,P1) { \
    h2 n1,e1,n2,e2,n3,e3,n4,e4;                    \
    PKTM(CA,CB, A1,B1, M1, n1,e1)                  \
    PKTM(CA,CB, A2,B2, M2, n2,e2)                  \
    PKTM(CA,CB, A3,B3, M3, n3,e3)                  \
    PKTM(CA,CB, A4,B4, M4, n4,e4)                  \
    h2 sA,eA,sB,eB,s4,e4t;                         \
    L1C(n1,e1,n2,e2, sA,eA)                        \
    L1C(n3,e3,n4,e4, sB,eB)                        \
    s4 = sA*eB + sB*eA; e4t = eA*eB;               \
    { float _sl = (float)s4[0], _sh = (float)s4[1];            \
      float _el = (float)e4t[0], _eh = (float)e4t[1];          \
      P0 = fmaf(_sl, __builtin_amdgcn_rcpf(_el), P0);          \
      P1 = fmaf(_sh, __builtin_amdgcn_rcpf(_eh), P1); } }

// load window row D into register set S (double-buffered pipeline)
#define LOADW_S(S, D)                                           \
    { const uint2* _pa = (const uint2*)(pa + (D) * SWP);        \
      const uint2* _pb = (const uint2*)(pb + (D) * SWP);        \
      uint2 _a0 = _pa[0], _a1 = _pa[1], _a2 = _pa[2];           \
      uint2 _b0 = _pb[0], _b1 = _pb[1], _b2 = _pb[2];           \
      wa0##S=_a0.x; wa1##S=_a0.y; wa2##S=_a1.x; wa3##S=_a1.y; wa4##S=_a2.x; wa5##S=_a2.y; \
      wb0##S=_b0.x; wb1##S=_b0.y; wb2##S=_b1.x; wb3##S=_b1.y; wb4##S=_b2.x; wb5##S=_b2.y; }

// aligns read from set S into the shared x-registers (consumed immediately)
#define ALIGNS_S(S)                                             \
    xa0 = __builtin_amdgcn_alignbit(wa1##S, wa0##S, 16);        \
    xa1 = __builtin_amdgcn_alignbit(wa2##S, wa1##S, 16);        \
    xa2 = __builtin_amdgcn_alignbit(wa3##S, wa2##S, 16);        \
    xa3 = __builtin_amdgcn_alignbit(wa4##S, wa3##S, 16);        \
    xa4 = __builtin_amdgcn_alignbit(wa5##S, wa4##S, 16);        \
    xb0 = __builtin_amdgcn_alignbit(wb1##S, wb0##S, 16);        \
    xb1 = __builtin_amdgcn_alignbit(wb2##S, wb1##S, 16);        \
    xb2 = __builtin_amdgcn_alignbit(wb3##S, wb2##S, 16);        \
    xb3 = __builtin_amdgcn_alignbit(wb4##S, wb3##S, 16);        \
    xb4 = __builtin_amdgcn_alignbit(wb5##S, wb4##S, 16);

// compute one lower row from register set S (row offset D for the ER mask)
#define LOWCOMP_S(S, D)                                         \
    { ALIGNS_S(S)                                               \
      float mv = 1.f;                                           \
      if constexpr (ER) mv = (gr + (D) < Hd) ? 1.f : 0.f;       \
      (void)mv;                                                 \
      ROWJOB(CA0,CB0, wa0##S,xa0,wa1##S,xa1,wa2##S,xa2,wa3##S,xa3,wa4##S,  \
                      wb0##S,xb0,wb1##S,xb1,wb2##S,xb2,wb3##S,xb3,wb4##S,  \
                      m_m4,m_m3,m_m2,m_m1,m_0,m_p1,m_p2,m_p3,m_p4, mv, p00,p01) \
      ROWJOB(CA1,CB1, wa1##S,xa1,wa2##S,xa2,wa3##S,xa3,wa4##S,xa4,wa5##S,  \
                      wb1##S,xb1,wb2##S,xb2,wb3##S,xb3,wb4##S,xb4,wb5##S,  \
                      m_m2,m_m1,m_0,m_p1,m_p2,m_p3,m_p4,m_p5,m_p6, mv, p10,p11) }

// one 4-px strip, 2-deep software-pipelined rows
template<bool EC, bool ER>
__device__ __forceinline__ float strip_sum(const unsigned* __restrict__ pa,
                                           const unsigned* __restrict__ pb,
                                           int ub, int gr)
{
    const h2 h05 = { (__fp16)0.5f, (__fp16)0.5f };
    unsigned m_m4=0,m_m3=0,m_m2=0,m_m1=0,m_0=0,m_p1=0,m_p2=0,m_p3=0,m_p4=0,m_p5=0,m_p6=0;
    if constexpr (EC) {
        auto mk = [&](int k)->unsigned {
            unsigned lo = ((unsigned)(ub + k)     < (unsigned)Wd) ? 0x3C00u : 0u;
            unsigned hi = ((unsigned)(ub + k + 1) < (unsigned)Wd) ? 0x3C00u : 0u;
            return lo | (hi << 16);
        };
        m_m4=mk(-4); m_m3=mk(-3); m_m2=mk(-2); m_m1=mk(-1); m_0=mk(0);
        m_p1=mk(1);  m_p2=mk(2);  m_p3=mk(3);  m_p4=mk(4);  m_p5=mk(5); m_p6=mk(6);
    }

    unsigned wa0A,wa1A,wa2A,wa3A,wa4A,wa5A, wb0A,wb1A,wb2A,wb3A,wb4A,wb5A;
    unsigned wa0B,wa1B,wa2B,wa3B,wa4B,wa5B, wb0B,wb1B,wb2B,wb3B,wb4B,wb5B;
    unsigned xa0,xa1,xa2,xa3,xa4, xb0,xb1,xb2,xb3,xb4;
    float p00=0.f, p01=0.f, p10=0.f, p11=0.f;

    // pipeline: load row0(A), row1(B) up front; then load D+1 before computing D
    LOADW_S(A, 0)
    LOADW_S(B, 1)

    // center row (set A)
    ALIGNS_S(A)
    h2 CA0 = u2h(wa2A), CB0 = u2h(wb2A);   // job 0 centers (px ub, ub+1)
    h2 CA1 = u2h(wa3A), CB1 = u2h(wb3A);   // job 1 centers (px ub+2, ub+3)
    CTR4(CA0,CB0, xa2,wa3A,xa3,wa4A, xb2,wb3A,xb3,wb4A, m_p1,m_p2,m_p3,m_p4, p00,p01)
    CTR4(CA1,CB1, xa3,wa4A,xa4,wa5A, xb3,wb4A,xb4,wb5A, m_p3,m_p4,m_p5,m_p6, p10,p11)

    LOADW_S(A, 2)      // prefetch row2 while computing row1
    LOWCOMP_S(B, 1)
    LOADW_S(B, 3)      // prefetch row3 while computing row2
    LOWCOMP_S(A, 2)
    LOADW_S(A, 4)      // prefetch row4 while computing row3
    LOWCOMP_S(B, 3)
    LOWCOMP_S(A, 4)

    return (p00 + p01) + (p10 + p11);
}

// ---------------- Kernel B: packed-pair census over 64x16 tiles ----------------
__global__ __launch_bounds__(256)
void census_pk(const float* __restrict__ proj, const float* __restrict__ im,
               float* __restrict__ partial)
{
    __shared__ unsigned sA[(TH + RR) * SWP];   // proj pairs
    __shared__ unsigned sB[(TH + RR) * SWP];   // im pairs

    const int tU = blockIdx.x, tV = blockIdx.y, b = blockIdx.z;
    const int tid = threadIdx.x;
    const float* pb = proj + (size_t)b * HWsz;
    const float* ib = im   + (size_t)b * HWsz;
    const int v0  = tV * TH;
    const int u0g = tU * TW - 4;               // LDS col0 global col (even)

    const bool edgeC = (tU == 0) | (tU == TILES_X - 1);
    const bool edgeR = (tV == TILES_Y - 1);

    if (!edgeC && !edgeR) {
        const float* pbase = pb + v0 * Wd + u0g;
        const float* ibase = ib + v0 * Wd + u0g;
        for (int f = tid; f < (TH + RR) * 18; f += 256) {
            int r = f / 18;
            int c4 = (f - 18 * r) * 4;
            float4 va = *(const float4*)(pbase + r * Wd + c4);
            float4 vb = *(const float4*)(ibase + r * Wd + c4);
            uint2 qa = { pack2(va.x, va.y), pack2(va.z, va.w) };
            uint2 qb = { pack2(vb.x, vb.y), pack2(vb.z, vb.w) };
            *(uint2*)&sA[r * SWP + c4 / 2] = qa;
            *(uint2*)&sB[r * SWP + c4 / 2] = qb;
        }
    } else {
        for (int p = tid; p < (TH + RR) * 36; p += 256) {
            int r = p / 36;
            int q = p - 36 * r;
            int gv = min(v0 + r, Hd - 1);
            int g0 = min(max(u0g + 2 * q,     0), Wd - 1);
            int g1 = min(max(u0g + 2 * q + 1, 0), Wd - 1);
            const float* pr   = pb + (size_t)gv * Wd;
            const float* irow = ib + (size_t)gv * Wd;
            sA[r * SWP + q] = pack2(pr[g0],   pr[g1]);
            sB[r * SWP + q] = pack2(irow[g0], irow[g1]);
        }
    }
    __syncthreads();

    const int ty = tid >> 4;                    // 0..15 (row in tile)
    const int tx = tid & 15;                    // 0..15 (group of 4 px = 2 pairs)
    const int ub = tU * TW + 4 * tx;            // global col of px 0
    const int gr = v0 + ty;

    const unsigned* pa = sA + ty * SWP + 2 * tx;
    const unsigned* pbp = sB + ty * SWP + 2 * tx;

    float acc;
    if (!edgeC && !edgeR)      acc = strip_sum<false,false>(pa, pbp, ub, gr);
    else if (edgeC && !edgeR)  acc = strip_sum<true, false>(pa, pbp, ub, gr);
    else if (!edgeC)           acc = strip_sum<false,true >(pa, pbp, ub, gr);
    else                       acc = strip_sum<true, true >(pa, pbp, ub, gr);

    // block reduction -> one partial per block (deterministic)
    #pragma unroll
    for (int o = 32; o; o >>= 1) acc += __shfl_down(acc, o);
    __shared__ float wsum[4];
    int wid = tid >> 6, lane = tid & 63;
    if (lane == 0) wsum[wid] = acc;
    __syncthreads();
    if (tid == 0) {
        float s = wsum[0] + wsum[1] + wsum[2] + wsum[3];
        partial[((int)blockIdx.z * gridDim.y + blockIdx.y) * gridDim.x + blockIdx.x] = s;
    }
}

// ---------------- Kernel C: final deterministic reduce ----------------
__global__ __launch_bounds__(1024)
void final_reduce(const float* __restrict__ partial, float* __restrict__ out)
{
    double s = 0.0;
    for (int i = threadIdx.x; i < NBLK; i += 1024) s += (double)partial[i];
    __shared__ double sm[1024];
    sm[threadIdx.x] = s;
    __syncthreads();
    for (int st = 512; st; st >>= 1) {
        if (threadIdx.x < st) sm[threadIdx.x] += sm[threadIdx.x + st];
        __syncthreads();
    }
    if (threadIdx.x == 0) {
        // val = 2 * S_half / (81 * B*H*W)   (half-space symmetry doubling)
        out[0] = (float)(sm[0] * (2.0 / (81.0 * (double)NB * Hd * Wd)));
    }
}

extern "C" void kernel_launch(void* const* d_in, const int* in_sizes, int n_in,
                              void* d_out, int out_size, void* d_ws, size_t ws_size,
                              hipStream_t stream)
{
    const float* disp    = (const float*)d_in[0];
    const float* im      = (const float*)d_in[1];
    const float* pattern = (const float*)d_in[2];
    float* out  = (float*)d_out;
    float* proj = out + 1;                      // output 1: pattern_proj
    float* partial = (float*)d_ws;              // 10240 floats scratch

    const int npx = NB * (int)HWsz;
    warp_kernel<<<npx / (256 * 4), 256, 0, stream>>>(disp, pattern, proj);

    dim3 grid(TILES_X, TILES_Y, NB);
    census_pk<<<grid, 256, 0, stream>>>(proj, im, partial);

    final_reduce<<<1, 1024, 0, stream>>>(partial, out);
}